// Round 3
// baseline (561.579 us; speedup 1.0000x reference)
//
#include <hip/hip_runtime.h>

// Problem constants
#define NB 16
#define NT 24
#define NH 96
#define NW 96
#define NC 8     // input channels
#define NF 16    // ConvLSTM filters
#define NG 64    // 4*NF gate channels
#define HW (NH*NW)
#define KPAD 224 // 144 (h: 9 taps x 16) + 72 (x: 9 taps x 8) + 8 zero pad
#define HSTR 24  // hs pixel stride in f16 (16 ch + 8 pad -> 48B, bank-friendly)

typedef _Float16 f16x8 __attribute__((ext_vector_type(8)));
typedef float    f32x4 __attribute__((ext_vector_type(4)));

// ---------------------------------------------------------------------------
// Pack both conv kernels, transposed + f16, into wT[n][k]:
//   k in [0,144):   wh, k = tap*16 + ci
//   k in [144,216): wx, k-144 = tap*8 + ci
//   k in [216,224): zero pad
// ---------------------------------------------------------------------------
__global__ __launch_bounds__(256) void prep_weights(
    const float* __restrict__ wx, const float* __restrict__ wh,
    _Float16* __restrict__ wT)
{
    const int idx = blockIdx.x * 256 + threadIdx.x;
    if (idx >= NG * KPAD) return;
    const int n = idx / KPAD;
    const int k = idx % KPAD;
    float v = 0.f;
    if (k < 144)      v = wh[k * NG + n];
    else if (k < 216) v = wx[(k - 144) * NG + n];
    wT[n * KPAD + k] = (_Float16)v;
}

// ---------------------------------------------------------------------------
// One ConvLSTM step, MFMA implicit-GEMM.
// Block: 16x16 pixel tile, 4 waves. Wave w: rows [4w,4w+4).
// B-fragments live in registers (112 VGPR); A comes from LDS via 7
// precomputed per-lane base pointers (no branch/div in the K loop).
// ---------------------------------------------------------------------------
__global__ __launch_bounds__(256, 2) void convlstm_step_mfma(
    const float* __restrict__ x,       // [B,T,H,W,C] fp32
    const _Float16* __restrict__ wT,   // [NG][KPAD]
    const float* __restrict__ bias,    // [NG]
    const _Float16* __restrict__ h_in, // [B,H,W,NF] f16
    _Float16* __restrict__ h_out,      // [B,H,W,NF] f16
    float* __restrict__ c,             // [B,H,W,NF] fp32, in place
    int t)
{
    __shared__ _Float16 hs[18 * 18 * HSTR];           // 15.2 KB halo'd h
    __shared__ _Float16 xs[18 * 18 * NC];             //  5.1 KB halo'd x
    __shared__ __align__(16) _Float16 zpad[8];        // zeros for K-pad reads

    const int tid  = threadIdx.x;
    const int wave = tid >> 6;
    const int lane = tid & 63;
    const int g    = lane >> 4;     // 0..3
    const int cl   = lane & 15;     // 0..15

    const int b    = blockIdx.x / 36;
    const int tile = blockIdx.x % 36;
    const int ty0  = (tile / 6) * 16;
    const int tx0  = (tile % 6) * 16;

    // ---- B fragments straight into registers (28 x 16B, L1/L2-hot) ----
    f16x8 bfr[7][4];
    #pragma unroll
    for (int cc = 0; cc < 7; ++cc)
        #pragma unroll
        for (int nf = 0; nf < 4; ++nf)
            bfr[cc][nf] = *(const f16x8*)&wT[(nf * 16 + cl) * KPAD + cc * 32 + g * 8];

    if (tid == 0) *(f16x8*)zpad = (f16x8)(_Float16)0.f;

    // ---- stage h halo (18x18 pixels), zero outside image ----
    const _Float16* hb = h_in + (size_t)b * HW * NF;
    for (int i = tid; i < 324; i += 256) {
        const int gy = ty0 + (i / 18) - 1;
        const int gx = tx0 + (i % 18) - 1;
        f16x8 v0 = (f16x8)(_Float16)0.f, v1 = v0;
        if (gy >= 0 && gy < NH && gx >= 0 && gx < NW) {
            const f16x8* src = (const f16x8*)(hb + ((size_t)gy * NW + gx) * NF);
            v0 = src[0]; v1 = src[1];
        }
        *(f16x8*)&hs[i * HSTR]     = v0;
        *(f16x8*)&hs[i * HSTR + 8] = v1;
    }

    // ---- stage x halo with fp32->f16 convert ----
    const float* xb = x + ((size_t)b * NT + t) * (size_t)HW * NC;
    for (int i = tid; i < 324; i += 256) {
        const int gy = ty0 + (i / 18) - 1;
        const int gx = tx0 + (i % 18) - 1;
        f16x8 v = (f16x8)(_Float16)0.f;
        if (gy >= 0 && gy < NH && gx >= 0 && gx < NW) {
            const float4* src = (const float4*)(xb + ((size_t)gy * NW + gx) * NC);
            float4 a0 = src[0], a1 = src[1];
            v[0] = (_Float16)a0.x; v[1] = (_Float16)a0.y;
            v[2] = (_Float16)a0.z; v[3] = (_Float16)a0.w;
            v[4] = (_Float16)a1.x; v[5] = (_Float16)a1.y;
            v[6] = (_Float16)a1.z; v[7] = (_Float16)a1.w;
        }
        *(f16x8*)&xs[i * NC] = v;
    }

    // ---- per-lane A base pointers / mf strides, hoisted out of K loop ----
    // khat = cc*32 + g*8 selects region: h [0,144), x [144,216), pad [216,224)
    const _Float16* abase[7];
    int astr[7];
    #pragma unroll
    for (int cc = 0; cc < 7; ++cc) {
        const int khat = cc * 32 + g * 8;
        if (khat < 144) {
            const int tap = khat >> 4, ci0 = khat & 15;
            abase[cc] = &hs[(((wave * 4) + tap / 3) * 18 + cl + tap % 3) * HSTR + ci0];
            astr[cc]  = 18 * HSTR;
        } else if (khat < 216) {
            const int tap = (khat - 144) >> 3;
            abase[cc] = &xs[(((wave * 4) + tap / 3) * 18 + cl + tap % 3) * NC];
            astr[cc]  = 18 * NC;
        } else {
            abase[cc] = zpad;
            astr[cc]  = 0;
        }
    }

    // ---- accumulators init with bias (D frag: n = nf*16 + cl) ----
    float bv[4];
    #pragma unroll
    for (int nf = 0; nf < 4; ++nf) bv[nf] = bias[nf * 16 + cl];
    f32x4 acc[4][4];
    #pragma unroll
    for (int mf = 0; mf < 4; ++mf)
        #pragma unroll
        for (int nf = 0; nf < 4; ++nf) acc[mf][nf] = (f32x4)bv[nf];

    __syncthreads();

    // ---- K loop: 7 chunks of 32; 4 ds_read_b128 + 16 MFMA each ----
    #pragma unroll
    for (int cc = 0; cc < 7; ++cc) {
        f16x8 afr[4];
        #pragma unroll
        for (int mf = 0; mf < 4; ++mf)
            afr[mf] = *(const f16x8*)(abase[cc] + mf * astr[cc]);
        #pragma unroll
        for (int mf = 0; mf < 4; ++mf)
            #pragma unroll
            for (int nf = 0; nf < 4; ++nf)
                acc[mf][nf] = __builtin_amdgcn_mfma_f32_16x16x32_f16(
                    afr[mf], bfr[cc][nf], acc[mf][nf], 0, 0, 0);
    }

    // ---- gates + state update ----
    // D frag: pixel (ty = 4*wave+mf, tx = 4*g+r), channel = cl, gate = nf.
    #pragma unroll
    for (int mf = 0; mf < 4; ++mf) {
        const int gy = ty0 + (wave << 2) + mf;
        #pragma unroll
        for (int r = 0; r < 4; ++r) {
            const int gx = tx0 + (g << 2) + r;
            const size_t pix = (size_t)b * HW + (size_t)gy * NW + gx;
            const float zi = acc[mf][0][r];
            const float zf = acc[mf][1][r];
            const float zc = acc[mf][2][r];
            const float zo = acc[mf][3][r];
            const float ig = fminf(fmaxf(0.2f * zi + 0.5f, 0.f), 1.f);
            const float fg = fminf(fmaxf(0.2f * zf + 0.5f, 0.f), 1.f);
            const float og = fminf(fmaxf(0.2f * zo + 0.5f, 0.f), 1.f);
            const float cold = c[pix * NF + cl];
            const float cn = fg * cold + ig * fmaxf(zc, 0.f);
            c[pix * NF + cl] = cn;
            h_out[pix * NF + cl] = (_Float16)(og * fmaxf(cn, 0.f));
        }
    }
}

// ---------------------------------------------------------------------------
// Fused inference-BatchNorm + Dense(1) on f16 h.
// ---------------------------------------------------------------------------
__global__ __launch_bounds__(256) void bn_dense(
    const _Float16* __restrict__ h,   // [B,H,W,NF] f16
    const float* __restrict__ gamma,
    const float* __restrict__ beta,
    const float* __restrict__ mean,
    const float* __restrict__ var,
    const float* __restrict__ dw,     // [NF,1]
    const float* __restrict__ db,     // [1]
    float* __restrict__ out)          // [B,H,W,1]
{
    const int p = blockIdx.x * 256 + threadIdx.x;
    if (p >= NB * HW) return;

    const f16x8* hp = (const f16x8*)(h + (size_t)p * NF);
    f16x8 h0 = hp[0], h1 = hp[1];
    float s = db[0];
    float dot = 0.f;
    #pragma unroll
    for (int k = 0; k < NF; ++k) {
        const float inv = gamma[k] / sqrtf(var[k] + 1e-3f);
        const float hv = (k < 8) ? (float)h0[k] : (float)h1[k - 8];
        s   += (beta[k] - mean[k] * inv) * dw[k];
        dot += hv * inv * dw[k];
    }
    out[p] = s + dot;
}

extern "C" void kernel_launch(void* const* d_in, const int* in_sizes, int n_in,
                              void* d_out, int out_size, void* d_ws, size_t ws_size,
                              hipStream_t stream) {
    const float* x     = (const float*)d_in[0];
    const float* wx    = (const float*)d_in[1];
    const float* wh    = (const float*)d_in[2];
    const float* bias  = (const float*)d_in[3];
    const float* gamma = (const float*)d_in[4];
    const float* beta  = (const float*)d_in[5];
    const float* mean  = (const float*)d_in[6];
    const float* var   = (const float*)d_in[7];
    const float* dw    = (const float*)d_in[8];
    const float* db    = (const float*)d_in[9];
    float* out = (float*)d_out;

    // ws layout: h0 f16 (4.72 MB) | h1 f16 (4.72 MB) | c f32 (9.44 MB) | wT f16
    const size_t nh = (size_t)NB * HW * NF;
    _Float16* h0 = (_Float16*)d_ws;
    _Float16* h1 = h0 + nh;
    float*    cc = (float*)(h1 + nh);
    _Float16* wT = (_Float16*)(cc + nh);

    hipMemsetAsync(h0, 0, nh * sizeof(_Float16), stream);
    hipMemsetAsync(cc, 0, nh * sizeof(float), stream);

    prep_weights<<<(NG * KPAD + 255) / 256, 256, 0, stream>>>(wx, wh, wT);

    const int blocks = NB * 36;               // 576
    for (int t = 0; t < NT; ++t) {
        const _Float16* hin  = (t & 1) ? h1 : h0;
        _Float16*       hout = (t & 1) ? h0 : h1;
        convlstm_step_mfma<<<blocks, 256, 0, stream>>>(x, wT, bias, hin, hout, cc, t);
    }
    // t=23 (odd) wrote h0
    bn_dense<<<NB * HW / 256, 256, 0, stream>>>(h0, gamma, beta, mean, var, dw, db, out);
}